// Round 7
// baseline (122.087 us; speedup 1.0000x reference)
//
#include <hip/hip_runtime.h>
#include <hip/hip_bf16.h>
#include <stdint.h>

// SimpleVectorQuantizer: vecs [16,32,128,64] f32, codebook [512,64] f32.
// Outputs (flat f32): vecs_hat [65536*64], z [65536] (as float), l_commit, l_codebook.
//
// Round 18: r17's split showed the ~61us "floor" is harness poison fills and
// the scan core alone is ~40us (issue math: ~5us) -> per-wave latency-bound
// at 2 waves/SIMD (ds_read latency + 3-deep MFMA chains + MFMA->VALU ranking
// dependency per tile). r13 already showed 4 waves/SIMD, but paid 2x GLOBAL
// B-traffic; with B LDS-resident (r16) extra waves are nearly free.
// This round: 1024 threads = 16 waves = 4 waves/SIMD, MT=1 (16 vec/wave),
// VPB=256, grid=256 (1 block/CU). Gather fused back as epilogue (r16 beat
// the r17 split by ~5us; now it has 16 waves of MLP). B image + swizzle +
// hi/lo MFMA chain + merge + exact-f64 rescue byte-identical to the proven
// absmax-0 path. VGPR must stay <=128 for 4 waves/SIMD: MT=1 state ~100.

#define VQ_K 64
#define VQ_S 512
#define NTHREADS 1024                    // 16 waves
#define NWAVES 16
#define MT 1                             // m-tiles per wave -> 16 vectors/wave
#define NST 4                            // ranking states per thread
#define VPB 256                          // vectors per block
#define NTILES 32                        // 512 codewords / 16 per tile
#define ROWB 256                         // B row: 64 hi bf16 + 64 lo bf16 (packed)
#define CELL 7.62939453125e-6f           // f32 ulp at ref-score magnitude ~64
#define GAP_THRESH (8.0f * CELL)

typedef __attribute__((ext_vector_type(8))) short bf16x8;
typedef __attribute__((ext_vector_type(4))) float f32x4;

static __device__ __forceinline__ unsigned short f2bf_rne(float f) {
    unsigned u = __float_as_uint(f);
    unsigned r = (u + 0x7fffu + ((u >> 16) & 1u)) >> 16;
    return (unsigned short)r;
}
static __device__ __forceinline__ float bf2f(unsigned short h) {
    return __uint_as_float(((unsigned)h) << 16);
}

// K1: one wave per codebook row; lane k handles element k. csq only + zero loss.
__global__ __launch_bounds__(256, 1) void vq_prep(
    const float* __restrict__ cb, float* __restrict__ csqg,
    float* __restrict__ out_loss) {
    if (blockIdx.x == 0 && threadIdx.x == 0) { out_loss[0] = 0.f; out_loss[1] = 0.f; }
    const int lane = threadIdx.x & 63;
    const int row = blockIdx.x * 4 + (threadIdx.x >> 6);
    float c = cb[(size_t)row * VQ_K + lane];
    double d = (double)c * (double)c;
#pragma unroll
    for (int off = 1; off <= 32; off <<= 1) d += __shfl_xor(d, off, 64);
    if (lane == 0) csqg[row] = (float)d;
}

// K2: all-LDS-resident B image, 16-wave MFMA scan + rescue + fused gather.
__global__ __launch_bounds__(NTHREADS, 1) void vq_mfma(
    const float* __restrict__ vecs, const float* __restrict__ codebook,
    const float* __restrict__ csqg,
    float* __restrict__ out_hat, float* __restrict__ out_z,
    float* __restrict__ out_loss, float inv_n) {
    __shared__ __align__(16) unsigned char blds[VQ_S * ROWB];  // 131072 B
    __shared__ float csq_sh[VQ_S];       // exact csq (rescue)
    __shared__ float csqn2_sh[VQ_S];     // -csq/2 (C-init for the scan)
    __shared__ float vsq_all[VPB];
    __shared__ int zsh[VPB];
    __shared__ int rlist[VPB];
    __shared__ int rn;
    __shared__ float loss_sh;

    const int tid = threadIdx.x;
    const int wave = tid >> 6;                    // 0..15
    const int lane = tid & 63;
    const int m = lane & 15;
    const int q = lane >> 4;
    const int blockbase = blockIdx.x * VPB;
    const int wavebase = blockbase + wave * 16;   // 16 vectors per wave

    if (tid == 0) { rn = 0; loss_sh = 0.f; }
    // csq tables: 512 entries.
    if (tid < VQ_S) {
        float c = csqg[tid];
        csq_sh[tid] = c;
        csqn2_sh[tid] = -0.5f * c;
    }
    // B image: thread pair (row = tid>>1) converts half a codebook row each.
    {
        const int row = tid >> 1;
        const int half = tid & 1;
        const float4* crow = (const float4*)(codebook + (size_t)row * VQ_K);
        const int xr = (row & 7) << 4;
        unsigned char* rowp = &blds[row * ROWB];
#pragma unroll
        for (int jj = 0; jj < 4; ++jj) {          // 4 chunks of 8 elems
            const int j = half * 4 + jj;
            float4 f0 = crow[2 * j];
            float4 f1 = crow[2 * j + 1];
            float w[8] = {f0.x, f0.y, f0.z, f0.w, f1.x, f1.y, f1.z, f1.w};
            bf16x8 hi8, lo8;
#pragma unroll
            for (int e = 0; e < 8; ++e) {
                unsigned short h = f2bf_rne(w[e]);
                hi8[e] = (short)h;
                lo8[e] = (short)f2bf_rne(w[e] - bf2f(h));
            }
            *(bf16x8*)(rowp + ((j * 16) ^ xr)) = hi8;          // hi: bytes [0,128)
            *(bf16x8*)(rowp + (128 + ((j * 16) ^ xr))) = lo8;  // lo: bytes [128,256)
        }
    }

    // ---- A fragments (bf16 split) + exact vsq: one vector per thread ----
    bf16x8 ah1, ah2, al1, al2;
    {
        const float* vp = vecs + (size_t)(wavebase + m) * VQ_K + q * 8;
        float4 a0 = ((const float4*)vp)[0];
        float4 a1 = ((const float4*)vp)[1];
        float4 b0 = ((const float4*)(vp + 32))[0];
        float4 b1 = ((const float4*)(vp + 32))[1];
        float w1[8] = {a0.x, a0.y, a0.z, a0.w, a1.x, a1.y, a1.z, a1.w};
        float w2[8] = {b0.x, b0.y, b0.z, b0.w, b1.x, b1.y, b1.z, b1.w};
        double p = 0.0;
#pragma unroll
        for (int j = 0; j < 8; ++j) {
            double d1 = (double)w1[j], d2 = (double)w2[j];
            p = fma(d1, d1, p); p = fma(d2, d2, p);
        }
        p += __shfl_xor(p, 16, 64);
        p += __shfl_xor(p, 32, 64);
        if (q == 0) vsq_all[wave * 16 + m] = (float)p;
#pragma unroll
        for (int j = 0; j < 8; ++j) {
            unsigned short h1 = f2bf_rne(w1[j]);
            unsigned short h2 = f2bf_rne(w2[j]);
            ah1[j] = (short)h1;
            ah2[j] = (short)h2;
            al1[j] = (short)f2bf_rne(w1[j] - bf2f(h1));
            al2[j] = (short)f2bf_rne(w2[j] - bf2f(h2));
        }
    }
    __syncthreads();   // B image + csq tables + vsq resident

    // ---- K-loop: pure LDS + MFMA + ranking. No barriers, no global. ----
    float t1u[NST], t2u[NST];
    int t1i[NST];
#pragma unroll
    for (int st = 0; st < NST; ++st) { t1u[st] = -3.4e38f; t2u[st] = -3.4e38f; t1i[st] = 0; }
    const f32x4 zero4 = {0.f, 0.f, 0.f, 0.f};
    const int xm = (m & 7) << 4;

#pragma unroll 4
    for (int t = 0; t < NTILES; ++t) {
        const unsigned char* rb = &blds[(t * 16 + m) * ROWB];
        bf16x8 c1 = *(const bf16x8*)(rb + ((q * 16) ^ xm));
        bf16x8 c2 = *(const bf16x8*)(rb + ((64 + q * 16) ^ xm));
        bf16x8 c3 = *(const bf16x8*)(rb + (128 + ((q * 16) ^ xm)));
        bf16x8 c4 = *(const bf16x8*)(rb + (128 + ((64 + q * 16) ^ xm)));

        const float mh = csqn2_sh[t * 16 + m];
        const f32x4 ci = {mh, mh, mh, mh};
        const int nidx = t * 16 + m;
        f32x4 accA = __builtin_amdgcn_mfma_f32_16x16x32_bf16(ah1, c1, zero4, 0, 0, 0);
        f32x4 accB = __builtin_amdgcn_mfma_f32_16x16x32_bf16(ah2, c2, ci, 0, 0, 0);
        accA = __builtin_amdgcn_mfma_f32_16x16x32_bf16(al1, c1, accA, 0, 0, 0);
        accB = __builtin_amdgcn_mfma_f32_16x16x32_bf16(al2, c2, accB, 0, 0, 0);
        accA = __builtin_amdgcn_mfma_f32_16x16x32_bf16(ah1, c3, accA, 0, 0, 0);
        accB = __builtin_amdgcn_mfma_f32_16x16x32_bf16(ah2, c4, accB, 0, 0, 0);
#pragma unroll
        for (int r = 0; r < 4; ++r) {
            float u = accA[r] + accB[r];
            bool gt = u > t1u[r];                          // strict: first index wins
            t2u[r] = fminf(fmaxf(u, t2u[r]), t1u[r]);      // 2nd-largest
            t1u[r] = fmaxf(t1u[r], u);
            t1i[r] = gt ? nidx : t1i[r];
        }
    }

    // ---- convert to score space (sc = -2u) and butterfly-merge 16 columns ----
    float t1s[NST], t2s[NST];
    unsigned long long pk[NST];
#pragma unroll
    for (int st = 0; st < NST; ++st) {
        t1s[st] = -2.0f * t1u[st];
        t2s[st] = -2.0f * t2u[st];
        unsigned u = __float_as_uint(t1s[st]);
        unsigned mono = (u & 0x80000000u) ? ~u : (u | 0x80000000u);
        pk[st] = ((unsigned long long)mono << 32) | (unsigned)t1i[st];
    }
#pragma unroll
    for (int dd = 1; dd <= 8; dd <<= 1) {
#pragma unroll
        for (int st = 0; st < NST; ++st) {
            unsigned long long opk = __shfl_xor(pk[st], dd, 64);
            float o1 = __shfl_xor(t1s[st], dd, 64);
            float o2 = __shfl_xor(t2s[st], dd, 64);
            t2s[st] = fminf(fmaxf(t1s[st], o1), fminf(t2s[st], o2));
            t1s[st] = fminf(t1s[st], o1);
            pk[st] = opk < pk[st] ? opk : pk[st];
        }
    }

    // ---- writers: lanes m<4 own state st=m -> vector wave*16 + q*4 + (m&3)
    float w1s = 3.4e38f, w2s = 3.4e38f;
    unsigned long long wpk = 0;
#pragma unroll
    for (int i = 0; i < NST; ++i) {
        bool sel = (m == i);
        w1s = sel ? t1s[i] : w1s;
        w2s = sel ? t2s[i] : w2s;
        wpk = sel ? pk[i] : wpk;
    }
    const bool writer = (m < NST);
    const int vloc = wave * 16 + q * 4 + (m & 3);
    float dl = 0.f;
    if (writer) {
        zsh[vloc] = (int)(wpk & 0xffffffffull);
        if (w2s - w1s <= GAP_THRESH) {
            int pos = atomicAdd(&rn, 1);
            rlist[pos] = vloc;
        }
        float full = vsq_all[vloc] + w1s;          // loss = relu(vsq + best)
        dl = (full < 0.f ? 0.f : full) * inv_n;
    }
#pragma unroll
    for (int off = 32; off >= 1; off >>= 1) dl += __shfl_down(dl, off, 64);
    if (lane == 0) atomicAdd(&loss_sh, dl);

    __syncthreads();

    // ---- in-block exact rescue (r3-proven arithmetic): wave w -> rlist[base+w]
    const int nr = rn;
    for (int rbase = 0; rbase < nr; rbase += NWAVES) {
        const int slot = rbase + wave;
        if (slot < nr) {                       // wave-uniform
            const int rv = rlist[slot];
            const float4* vrow4 = (const float4*)(vecs + (size_t)(blockbase + rv) * VQ_K);
            const float vsqr = vsq_all[rv];
            unsigned long long best = ~0ull;
            for (int j = 0; j < 8; ++j) {
                const int s = lane * 8 + j;
                const float4* crow = (const float4*)(codebook + (size_t)s * VQ_K);
                double acc = 0.0;
#pragma unroll
                for (int qq = 0; qq < VQ_K / 4; ++qq) {
                    float4 c = crow[qq];
                    float4 tt = vrow4[qq];     // wave-uniform -> scalar loads
                    acc = fma((double)c.x, (double)tt.x, acc);
                    acc = fma((double)c.y, (double)tt.y, acc);
                    acc = fma((double)c.z, (double)tt.z, acc);
                    acc = fma((double)c.w, (double)tt.w, acc);
                }
                float e = (float)acc;
                float sc = fmaf(-2.0f, e, vsqr) + csq_sh[s];   // exact ref rounding
                unsigned u = __float_as_uint(sc);
                unsigned mono = (u & 0x80000000u) ? ~u : (u | 0x80000000u);
                unsigned long long pkr = ((unsigned long long)mono << 32) | (unsigned)s;
                best = pkr < best ? pkr : best;
            }
#pragma unroll
            for (int off = 32; off >= 1; off >>= 1) {
                unsigned long long o = __shfl_down(best, off, 64);
                best = o < best ? o : best;
            }
            if (lane == 0) zsh[rv] = (int)(best & 0xffffffffull);
        }
    }
    __syncthreads();

    // ---- loss atomics (2/block), coalesced z write + fused gather ----
    if (tid == 0) {
        float l = loss_sh;
        atomicAdd(&out_loss[0], l);
        atomicAdd(&out_loss[1], l);
    }
    if (tid < VPB) out_z[blockbase + tid] = (float)zsh[tid];
    const float4* cb4g = (const float4*)codebook;
    float4* hat4 = (float4*)(out_hat + (size_t)blockbase * VQ_K);
    const int F = VPB * (VQ_K / 4);                // 4096
#pragma unroll
    for (int f = tid; f < F; f += NTHREADS) {
        int vv = f >> 4;
        int k4 = f & 15;
        hat4[f] = cb4g[zsh[vv] * (VQ_K / 4) + k4];
    }
}

extern "C" void kernel_launch(void* const* d_in, const int* in_sizes, int n_in,
                              void* d_out, int out_size, void* d_ws, size_t ws_size,
                              hipStream_t stream) {
    const float* vecs = (const float*)d_in[0];
    const float* codebook = (const float*)d_in[1];
    float* out = (float*)d_out;

    const int nvec = in_sizes[0] / VQ_K;            // 65536
    float* csqg = (float*)d_ws;                     // 2048 B

    float* out_hat = out;
    float* out_z = out + (size_t)nvec * VQ_K;
    float* out_loss = out + out_size - 2;

    vq_prep<<<VQ_S / 4, 256, 0, stream>>>(codebook, csqg, out_loss);
    vq_mfma<<<nvec / VPB, NTHREADS, 0, stream>>>(
        vecs, codebook, csqg, out_hat, out_z, out_loss, 1.0f / (float)nvec);
}

// Round 8
// 101.596 us; speedup vs baseline: 1.2017x; 1.2017x over previous
//
#include <hip/hip_runtime.h>
#include <hip/hip_bf16.h>
#include <stdint.h>

// SimpleVectorQuantizer: vecs [16,32,128,64] f32, codebook [512,64] f32.
// Outputs (flat f32): vecs_hat [65536*64], z [65536] (as float), l_commit, l_codebook.
//
// Round 19: r18 re-confirmed the unified-file wall (1024thr -> 128-reg budget
// -> VGPR 64 + 9MB spill). Stable point: 512thr, 2 waves/SIMD, VGPR~88.
// Remaining theory: kernel time ~= HBM traffic (26MB) at ~550 GB/s because
// the memory PHASES are MLP-starved: the A-prologue interleaves each load
// pair with a 16-deep f64 chain + conversions (compiler drains vmcnt almost
// immediately -> ~1-2 vmem instrs in flight), and the gather epilogue is a
// serial LDS->global->store chain. Fix (T14 x2, numerics untouched):
//   1) issue ALL 8 A float4 loads first; B-image build (ALU-heavy) runs
//      while they fly; conversions consume them afterwards.
//   2) epilogue: batch-read 8 zsh from LDS, issue all 8 gather loads, then
//      8 stores -> 8-deep MLP.
// Everything else is the r16 LDS-resident structure (512thr, grid=256,
// 1 block/CU, B image + XOR swizzle + hi/lo MFMA chain + packed-key merge +
// exact-f64 rescue + fused gather), absmax-0 proven.

#define VQ_K 64
#define VQ_S 512
#define NTHREADS 512                     // 8 waves
#define MT 2                             // m-tiles per wave -> 32 vectors/wave
#define VPB 256                          // vectors per block
#define NTILES 32                        // 512 codewords / 16 per tile
#define ROWB 256                         // B row: 64 hi bf16 + 64 lo bf16 (packed)
#define CELL 7.62939453125e-6f           // f32 ulp at ref-score magnitude ~64
#define GAP_THRESH (8.0f * CELL)

typedef __attribute__((ext_vector_type(8))) short bf16x8;
typedef __attribute__((ext_vector_type(4))) float f32x4;

static __device__ __forceinline__ unsigned short f2bf_rne(float f) {
    unsigned u = __float_as_uint(f);
    unsigned r = (u + 0x7fffu + ((u >> 16) & 1u)) >> 16;
    return (unsigned short)r;
}
static __device__ __forceinline__ float bf2f(unsigned short h) {
    return __uint_as_float(((unsigned)h) << 16);
}

// K1: one wave per codebook row; lane k handles element k. csq only + zero loss.
__global__ __launch_bounds__(256, 1) void vq_prep(
    const float* __restrict__ cb, float* __restrict__ csqg,
    float* __restrict__ out_loss) {
    if (blockIdx.x == 0 && threadIdx.x == 0) { out_loss[0] = 0.f; out_loss[1] = 0.f; }
    const int lane = threadIdx.x & 63;
    const int row = blockIdx.x * 4 + (threadIdx.x >> 6);
    float c = cb[(size_t)row * VQ_K + lane];
    double d = (double)c * (double)c;
#pragma unroll
    for (int off = 1; off <= 32; off <<= 1) d += __shfl_xor(d, off, 64);
    if (lane == 0) csqg[row] = (float)d;
}

// K2: all-LDS-resident B image, MLP-batched memory phases.
__global__ __launch_bounds__(NTHREADS, 1) void vq_mfma(
    const float* __restrict__ vecs, const float* __restrict__ codebook,
    const float* __restrict__ csqg,
    float* __restrict__ out_hat, float* __restrict__ out_z,
    float* __restrict__ out_loss, float inv_n) {
    __shared__ __align__(16) unsigned char blds[VQ_S * ROWB];  // 131072 B
    __shared__ float csq_sh[VQ_S];       // exact csq (rescue)
    __shared__ float csqn2_sh[VQ_S];     // -csq/2 (C-init for the scan)
    __shared__ float vsq_all[VPB];
    __shared__ int zsh[VPB];
    __shared__ int rlist[VPB];
    __shared__ int rn;
    __shared__ float loss_sh;

    const int tid = threadIdx.x;
    const int wave = tid >> 6;                    // 0..7
    const int lane = tid & 63;
    const int m = lane & 15;
    const int q = lane >> 4;
    const int blockbase = blockIdx.x * VPB;
    const int wavebase = blockbase + wave * 32;   // 32 vectors per wave

    if (tid == 0) { rn = 0; loss_sh = 0.f; }

    // ---- ISSUE ALL A LOADS FIRST (8 x float4, max per-wave MLP) ----
    const float* vp0 = vecs + (size_t)(wavebase + m) * VQ_K + q * 8;
    const float* vp1 = vecs + (size_t)(wavebase + 16 + m) * VQ_K + q * 8;
    float4 A0a = ((const float4*)vp0)[0];
    float4 A0b = ((const float4*)vp0)[1];
    float4 A0c = ((const float4*)(vp0 + 32))[0];
    float4 A0d = ((const float4*)(vp0 + 32))[1];
    float4 A1a = ((const float4*)vp1)[0];
    float4 A1b = ((const float4*)vp1)[1];
    float4 A1c = ((const float4*)(vp1 + 32))[0];
    float4 A1d = ((const float4*)(vp1 + 32))[1];

    // csq tables (512 entries, 512 threads).
    {
        float c = csqg[tid];
        csq_sh[tid] = c;
        csqn2_sh[tid] = -0.5f * c;
    }
    // B image build runs while A loads are in flight.
    {
        const int row = tid;
        const float4* crow = (const float4*)(codebook + (size_t)row * VQ_K);
        const int xr = (row & 7) << 4;
        unsigned char* rowp = &blds[row * ROWB];
#pragma unroll
        for (int j = 0; j < 8; ++j) {             // 8 chunks of 8 elems
            float4 f0 = crow[2 * j];
            float4 f1 = crow[2 * j + 1];
            float w[8] = {f0.x, f0.y, f0.z, f0.w, f1.x, f1.y, f1.z, f1.w};
            bf16x8 hi8, lo8;
#pragma unroll
            for (int e = 0; e < 8; ++e) {
                unsigned short h = f2bf_rne(w[e]);
                hi8[e] = (short)h;
                lo8[e] = (short)f2bf_rne(w[e] - bf2f(h));
            }
            *(bf16x8*)(rowp + ((j * 16) ^ xr)) = hi8;          // hi: bytes [0,128)
            *(bf16x8*)(rowp + (128 + ((j * 16) ^ xr))) = lo8;  // lo: bytes [128,256)
        }
    }

    // ---- A fragments (bf16 split) + exact vsq (consume staged loads) ----
    bf16x8 ah1[MT], ah2[MT], al1[MT], al2[MT];
#pragma unroll
    for (int mt = 0; mt < MT; ++mt) {
        float4 a0 = (mt == 0) ? A0a : A1a;
        float4 a1 = (mt == 0) ? A0b : A1b;
        float4 b0 = (mt == 0) ? A0c : A1c;
        float4 b1 = (mt == 0) ? A0d : A1d;
        float w1[8] = {a0.x, a0.y, a0.z, a0.w, a1.x, a1.y, a1.z, a1.w};
        float w2[8] = {b0.x, b0.y, b0.z, b0.w, b1.x, b1.y, b1.z, b1.w};
        double p = 0.0;
#pragma unroll
        for (int j = 0; j < 8; ++j) {
            double d1 = (double)w1[j], d2 = (double)w2[j];
            p = fma(d1, d1, p); p = fma(d2, d2, p);
        }
        p += __shfl_xor(p, 16, 64);
        p += __shfl_xor(p, 32, 64);
        if (q == 0) vsq_all[wave * 32 + mt * 16 + m] = (float)p;
#pragma unroll
        for (int j = 0; j < 8; ++j) {
            unsigned short h1 = f2bf_rne(w1[j]);
            unsigned short h2 = f2bf_rne(w2[j]);
            ah1[mt][j] = (short)h1;
            ah2[mt][j] = (short)h2;
            al1[mt][j] = (short)f2bf_rne(w1[j] - bf2f(h1));
            al2[mt][j] = (short)f2bf_rne(w2[j] - bf2f(h2));
        }
    }
    __syncthreads();   // B image + csq tables + vsq resident

    // ---- K-loop: pure LDS + MFMA + ranking. No barriers, no global. ----
    float t1u[8], t2u[8];
    int t1i[8];
#pragma unroll
    for (int st = 0; st < 8; ++st) { t1u[st] = -3.4e38f; t2u[st] = -3.4e38f; t1i[st] = 0; }
    const f32x4 zero4 = {0.f, 0.f, 0.f, 0.f};
    const int xm = (m & 7) << 4;

#pragma unroll 4
    for (int t = 0; t < NTILES; ++t) {
        const unsigned char* rb = &blds[(t * 16 + m) * ROWB];
        bf16x8 c1 = *(const bf16x8*)(rb + ((q * 16) ^ xm));
        bf16x8 c2 = *(const bf16x8*)(rb + ((64 + q * 16) ^ xm));
        bf16x8 c3 = *(const bf16x8*)(rb + (128 + ((q * 16) ^ xm)));
        bf16x8 c4 = *(const bf16x8*)(rb + (128 + ((64 + q * 16) ^ xm)));

        const float mh = csqn2_sh[t * 16 + m];
        const f32x4 ci = {mh, mh, mh, mh};
        const int nidx = t * 16 + m;
#pragma unroll
        for (int mt = 0; mt < MT; ++mt) {
            f32x4 accA = __builtin_amdgcn_mfma_f32_16x16x32_bf16(ah1[mt], c1, zero4, 0, 0, 0);
            f32x4 accB = __builtin_amdgcn_mfma_f32_16x16x32_bf16(ah2[mt], c2, ci, 0, 0, 0);
            accA = __builtin_amdgcn_mfma_f32_16x16x32_bf16(al1[mt], c1, accA, 0, 0, 0);
            accB = __builtin_amdgcn_mfma_f32_16x16x32_bf16(al2[mt], c2, accB, 0, 0, 0);
            accA = __builtin_amdgcn_mfma_f32_16x16x32_bf16(ah1[mt], c3, accA, 0, 0, 0);
            accB = __builtin_amdgcn_mfma_f32_16x16x32_bf16(ah2[mt], c4, accB, 0, 0, 0);
#pragma unroll
            for (int r = 0; r < 4; ++r) {
                const int st = mt * 4 + r;
                float u = accA[r] + accB[r];
                bool gt = u > t1u[st];                          // strict: first index wins
                t2u[st] = fminf(fmaxf(u, t2u[st]), t1u[st]);    // 2nd-largest
                t1u[st] = fmaxf(t1u[st], u);
                t1i[st] = gt ? nidx : t1i[st];
            }
        }
    }

    // ---- convert to score space (sc = -2u) and butterfly-merge 16 columns ----
    float t1s[8], t2s[8];
    unsigned long long pk[8];
#pragma unroll
    for (int st = 0; st < 8; ++st) {
        t1s[st] = -2.0f * t1u[st];
        t2s[st] = -2.0f * t2u[st];
        unsigned u = __float_as_uint(t1s[st]);
        unsigned mono = (u & 0x80000000u) ? ~u : (u | 0x80000000u);
        pk[st] = ((unsigned long long)mono << 32) | (unsigned)t1i[st];
    }
#pragma unroll
    for (int dd = 1; dd <= 8; dd <<= 1) {
#pragma unroll
        for (int st = 0; st < 8; ++st) {
            unsigned long long opk = __shfl_xor(pk[st], dd, 64);
            float o1 = __shfl_xor(t1s[st], dd, 64);
            float o2 = __shfl_xor(t2s[st], dd, 64);
            t2s[st] = fminf(fmaxf(t1s[st], o1), fminf(t2s[st], o2));
            t1s[st] = fminf(t1s[st], o1);
            pk[st] = opk < pk[st] ? opk : pk[st];
        }
    }

    // ---- writers: lanes m<8 own state st=m -> vector wave*32+(m>>2)*16+q*4+(m&3)
    float w1s = 3.4e38f, w2s = 3.4e38f;
    unsigned long long wpk = 0;
#pragma unroll
    for (int i = 0; i < 8; ++i) {
        bool sel = (m == i);
        w1s = sel ? t1s[i] : w1s;
        w2s = sel ? t2s[i] : w2s;
        wpk = sel ? pk[i] : wpk;
    }
    const bool writer = (m < 8);
    const int vloc = wave * 32 + ((m >> 2) & 1) * 16 + q * 4 + (m & 3);
    float dl = 0.f;
    if (writer) {
        zsh[vloc] = (int)(wpk & 0xffffffffull);
        if (w2s - w1s <= GAP_THRESH) {
            int pos = atomicAdd(&rn, 1);
            rlist[pos] = vloc;
        }
        float full = vsq_all[vloc] + w1s;          // loss = relu(vsq + best)
        dl = (full < 0.f ? 0.f : full) * inv_n;
    }
#pragma unroll
    for (int off = 32; off >= 1; off >>= 1) dl += __shfl_down(dl, off, 64);
    if (lane == 0) atomicAdd(&loss_sh, dl);

    __syncthreads();

    // ---- in-block exact rescue (r3-proven arithmetic): wave w -> rlist[base+w]
    const int nr = rn;
    for (int rbase = 0; rbase < nr; rbase += 8) {
        const int slot = rbase + wave;
        if (slot < nr) {                       // wave-uniform
            const int rv = rlist[slot];
            const float4* vrow4 = (const float4*)(vecs + (size_t)(blockbase + rv) * VQ_K);
            const float vsqr = vsq_all[rv];
            unsigned long long best = ~0ull;
            for (int j = 0; j < 8; ++j) {
                const int s = lane * 8 + j;
                const float4* crow = (const float4*)(codebook + (size_t)s * VQ_K);
                double acc = 0.0;
#pragma unroll
                for (int qq = 0; qq < VQ_K / 4; ++qq) {
                    float4 c = crow[qq];
                    float4 tt = vrow4[qq];     // wave-uniform -> scalar loads
                    acc = fma((double)c.x, (double)tt.x, acc);
                    acc = fma((double)c.y, (double)tt.y, acc);
                    acc = fma((double)c.z, (double)tt.z, acc);
                    acc = fma((double)c.w, (double)tt.w, acc);
                }
                float e = (float)acc;
                float sc = fmaf(-2.0f, e, vsqr) + csq_sh[s];   // exact ref rounding
                unsigned u = __float_as_uint(sc);
                unsigned mono = (u & 0x80000000u) ? ~u : (u | 0x80000000u);
                unsigned long long pkr = ((unsigned long long)mono << 32) | (unsigned)s;
                best = pkr < best ? pkr : best;
            }
#pragma unroll
            for (int off = 32; off >= 1; off >>= 1) {
                unsigned long long o = __shfl_down(best, off, 64);
                best = o < best ? o : best;
            }
            if (lane == 0) zsh[rv] = (int)(best & 0xffffffffull);
        }
    }
    __syncthreads();

    // ---- loss atomics (2/block), coalesced z write + MLP-batched gather ----
    if (tid == 0) {
        float l = loss_sh;
        atomicAdd(&out_loss[0], l);
        atomicAdd(&out_loss[1], l);
    }
    if (tid < VPB) out_z[blockbase + tid] = (float)zsh[tid];
    {
        const float4* cb4g = (const float4*)codebook;
        float4* hat4 = (float4*)(out_hat + (size_t)blockbase * VQ_K);
        // stage 1: read the 8 needed z values from LDS
        int zz[8];
#pragma unroll
        for (int i = 0; i < 8; ++i) zz[i] = zsh[(tid + i * NTHREADS) >> 4];
        // stage 2: issue all 8 gather loads (independent, 8-deep MLP)
        float4 gv[8];
#pragma unroll
        for (int i = 0; i < 8; ++i) {
            const int f = tid + i * NTHREADS;
            gv[i] = cb4g[zz[i] * (VQ_K / 4) + (f & 15)];
        }
        // stage 3: stores
#pragma unroll
        for (int i = 0; i < 8; ++i) hat4[tid + i * NTHREADS] = gv[i];
    }
}

extern "C" void kernel_launch(void* const* d_in, const int* in_sizes, int n_in,
                              void* d_out, int out_size, void* d_ws, size_t ws_size,
                              hipStream_t stream) {
    const float* vecs = (const float*)d_in[0];
    const float* codebook = (const float*)d_in[1];
    float* out = (float*)d_out;

    const int nvec = in_sizes[0] / VQ_K;            // 65536
    float* csqg = (float*)d_ws;                     // 2048 B

    float* out_hat = out;
    float* out_z = out + (size_t)nvec * VQ_K;
    float* out_loss = out + out_size - 2;

    vq_prep<<<VQ_S / 4, 256, 0, stream>>>(codebook, csqg, out_loss);
    vq_mfma<<<nvec / VPB, NTHREADS, 0, stream>>>(
        vecs, codebook, csqg, out_hat, out_z, out_loss, 1.0f / (float)nvec);
}